// Round 7
// baseline (598.933 us; speedup 1.0000x reference)
//
#include <hip/hip_runtime.h>
#include <math.h>

// Geometry:
//   A = hidden_states [M=65536, K=512] fp32
//   W = w_qkv [N=1536, K=512] fp32, bias [1536]
//   qkv = A @ W^T + bias  -> [65536,1536] fp32 in d_ws
//   pass 2: scrambled elementwise softmax -> out [16,64,64,512] fp32
//
// GEMM: fp16 2-term split-MFMA (A = Ah + Al fp16; W -> fp16, RTZ).
// Depth-2 register prefetch with STATICALLY NAMED register sets (rule #20:
// runtime-indexed ext_vector arrays spill to scratch — round 6 showed
// WRITE_SIZE +220MB from exactly that). Manual 2-step loop body.

typedef _Float16 half8 __attribute__((ext_vector_type(8)));
typedef __fp16 fp16x2 __attribute__((ext_vector_type(2)));
typedef float f32x4 __attribute__((ext_vector_type(4)));

__device__ __forceinline__ half8 pk8(const float4 x, const float4 y) {
    fp16x2 a = __builtin_amdgcn_cvt_pkrtz(x.x, x.y);
    fp16x2 b = __builtin_amdgcn_cvt_pkrtz(x.z, x.w);
    fp16x2 c = __builtin_amdgcn_cvt_pkrtz(y.x, y.y);
    fp16x2 d = __builtin_amdgcn_cvt_pkrtz(y.z, y.w);
    half8 r;
    r[0] = (_Float16)a[0]; r[1] = (_Float16)a[1];
    r[2] = (_Float16)b[0]; r[3] = (_Float16)b[1];
    r[4] = (_Float16)c[0]; r[5] = (_Float16)c[1];
    r[6] = (_Float16)d[0]; r[7] = (_Float16)d[1];
    return r;
}
__device__ __forceinline__ void pk8_hilo(const float4 x, const float4 y,
                                         half8& h, half8& l) {
    h = pk8(x, y);
    float4 rx, ry;
    rx.x = x.x - (float)h[0]; rx.y = x.y - (float)h[1];
    rx.z = x.z - (float)h[2]; rx.w = x.w - (float)h[3];
    ry.x = y.x - (float)h[4]; ry.y = y.y - (float)h[5];
    ry.z = y.z - (float)h[6]; ry.w = y.w - (float)h[7];
    l = pk8(rx, ry);
}

// ---------------------------------------------------------------------------
// Kernel 1: C[65536,1536] = A @ W^T + bias.
// BM=BN=128, BK=32, 256 threads (2x2 waves, 64x64/wave), LDS double-buffered.
// Per buffer (halfword offsets): Ah [0,4096), Al [4096,8192), Wh [8192,12288).
// Chunk swizzle: 16B chunk c of row r stored at phys c ^ ((r>>1)&1).
// ---------------------------------------------------------------------------
__global__ __launch_bounds__(256, 3) void gemm_qkv_f16x2(
    const float* __restrict__ A,
    const float* __restrict__ W,
    const float* __restrict__ bias,
    float* __restrict__ C)
{
    __shared__ __align__(16) _Float16 lds[24576];   // 48 KB (2 x 24 KB)

    // XCD swizzle: 6144 blocks (%8==0), n-fastest within an XCD for A reuse
    const int lin = blockIdx.x;
    const int swz = (lin & 7) * 768 + (lin >> 3);
    const int nt = swz % 12, mt = swz / 12;
    const int row0 = mt * 128, col0 = nt * 128;

    const int tid  = threadIdx.x;
    const int wid  = tid >> 6;
    const int lane = tid & 63;
    const int wm   = wid >> 1;    // 0..1
    const int wn   = wid & 1;     // 0..1
    const int l15  = lane & 15;
    const int kq   = lane >> 4;   // 0..3

    // staging: thread t covers row ra = t>>1 (A and W rows), k = kh..kh+15
    const int ra = tid >> 1;
    const int kh = (tid & 1) * 16;
    const float* Ag = A + (size_t)(row0 + ra) * 512 + kh;
    const float* Wg = W + (size_t)(col0 + ra) * 512 + kh;
    const int rs  = (ra >> 1) & 1;             // row swizzle bit
    const int wc0 = (((kh >> 3) + 0) ^ rs) * 8;
    const int wc1 = (((kh >> 3) + 1) ^ rs) * 8;

    f32x4 acc[4][4];
#pragma unroll
    for (int i = 0; i < 4; ++i)
#pragma unroll
        for (int j = 0; j < 4; ++j) acc[i][j] = (f32x4)0.f;

    // depth-2 prefetch: two STATICALLY NAMED register sets (no runtime index)
    float4 a0_0, a0_1, a0_2, a0_3, w0_0, w0_1, w0_2, w0_3;   // set 0
    float4 a1_0, a1_1, a1_2, a1_3, w1_0, w1_1, w1_2, w1_3;   // set 1
    a0_0 = *reinterpret_cast<const float4*>(Ag + 0);
    a0_1 = *reinterpret_cast<const float4*>(Ag + 4);
    a0_2 = *reinterpret_cast<const float4*>(Ag + 8);
    a0_3 = *reinterpret_cast<const float4*>(Ag + 12);
    w0_0 = *reinterpret_cast<const float4*>(Wg + 0);
    w0_1 = *reinterpret_cast<const float4*>(Wg + 4);
    w0_2 = *reinterpret_cast<const float4*>(Wg + 8);
    w0_3 = *reinterpret_cast<const float4*>(Wg + 12);
    a1_0 = *reinterpret_cast<const float4*>(Ag + 32);
    a1_1 = *reinterpret_cast<const float4*>(Ag + 36);
    a1_2 = *reinterpret_cast<const float4*>(Ag + 40);
    a1_3 = *reinterpret_cast<const float4*>(Ag + 44);
    w1_0 = *reinterpret_cast<const float4*>(Wg + 32);
    w1_1 = *reinterpret_cast<const float4*>(Wg + 36);
    w1_2 = *reinterpret_cast<const float4*>(Wg + 40);
    w1_3 = *reinterpret_cast<const float4*>(Wg + 44);

#define STEP(IT, AR0, AR1, AR2, AR3, WR0, WR1, WR2, WR3, BUF)                  \
    do {                                                                       \
        _Float16* bp = lds + (BUF) * 12288;                                    \
        half8 h0, l0, h1, l1;                                                  \
        pk8_hilo(AR0, AR1, h0, l0);                                            \
        pk8_hilo(AR2, AR3, h1, l1);                                            \
        const half8 wv0 = pk8(WR0, WR1);                                       \
        const half8 wv1 = pk8(WR2, WR3);                                       \
        *reinterpret_cast<half8*>(bp + ra * 32 + wc0)        = h0;             \
        *reinterpret_cast<half8*>(bp + ra * 32 + wc1)        = h1;             \
        *reinterpret_cast<half8*>(bp + 4096 + ra * 32 + wc0) = l0;             \
        *reinterpret_cast<half8*>(bp + 4096 + ra * 32 + wc1) = l1;             \
        *reinterpret_cast<half8*>(bp + 8192 + ra * 32 + wc0) = wv0;            \
        *reinterpret_cast<half8*>(bp + 8192 + ra * 32 + wc1) = wv1;            \
        if ((IT) < 14) {                                                       \
            const int kb = ((IT) + 2) * 32;                                    \
            AR0 = *reinterpret_cast<const float4*>(Ag + kb + 0);               \
            AR1 = *reinterpret_cast<const float4*>(Ag + kb + 4);               \
            AR2 = *reinterpret_cast<const float4*>(Ag + kb + 8);               \
            AR3 = *reinterpret_cast<const float4*>(Ag + kb + 12);              \
            WR0 = *reinterpret_cast<const float4*>(Wg + kb + 0);               \
            WR1 = *reinterpret_cast<const float4*>(Wg + kb + 4);               \
            WR2 = *reinterpret_cast<const float4*>(Wg + kb + 8);               \
            WR3 = *reinterpret_cast<const float4*>(Wg + kb + 12);              \
        }                                                                      \
        __syncthreads();                                                       \
        const _Float16* cp = lds + (BUF) * 12288;                              \
        half8 ah[4], al[4];                                                    \
        _Pragma("unroll")                                                      \
        for (int mf = 0; mf < 4; ++mf) {                                       \
            const int r  = wm * 64 + mf * 16 + l15;                            \
            const int ph = (kq ^ ((r >> 1) & 1)) * 8;                          \
            ah[mf] = *reinterpret_cast<const half8*>(cp + r * 32 + ph);        \
            al[mf] = *reinterpret_cast<const half8*>(cp + 4096 + r * 32 + ph); \
        }                                                                      \
        _Pragma("unroll")                                                      \
        for (int nf = 0; nf < 4; ++nf) {                                       \
            const int rb = wn * 64 + nf * 16 + l15;                            \
            const int ph = (kq ^ ((rb >> 1) & 1)) * 8;                         \
            const half8 wv =                                                   \
                *reinterpret_cast<const half8*>(cp + 8192 + rb * 32 + ph);     \
            _Pragma("unroll")                                                  \
            for (int mf = 0; mf < 4; ++mf) {                                   \
                acc[mf][nf] = __builtin_amdgcn_mfma_f32_16x16x32_f16(          \
                    ah[mf], wv, acc[mf][nf], 0, 0, 0);                         \
                acc[mf][nf] = __builtin_amdgcn_mfma_f32_16x16x32_f16(          \
                    al[mf], wv, acc[mf][nf], 0, 0, 0);                         \
            }                                                                  \
        }                                                                      \
    } while (0)

    for (int it = 0; it < 16; it += 2) {
        STEP(it,     a0_0, a0_1, a0_2, a0_3, w0_0, w0_1, w0_2, w0_3, 0);
        STEP(it + 1, a1_0, a1_1, a1_2, a1_3, w1_0, w1_1, w1_2, w1_3, 1);
    }
#undef STEP

    // epilogue: C/D layout col = lane&15, row = (lane>>4)*4 + j
    float bv[4];
#pragma unroll
    for (int nf = 0; nf < 4; ++nf)
        bv[nf] = bias[col0 + wn * 64 + nf * 16 + l15];

#pragma unroll
    for (int mf = 0; mf < 4; ++mf)
#pragma unroll
        for (int nf = 0; nf < 4; ++nf) {
            const int c = col0 + wn * 64 + nf * 16 + l15;
#pragma unroll
            for (int j = 0; j < 4; ++j) {
                const int r = row0 + wm * 64 + mf * 16 + kq * 4 + j;
                C[(size_t)r * 1536 + c] = acc[mf][nf][j] + bv[nf];
            }
        }
}

// ---------------------------------------------------------------------------
// Kernel 2: scrambled elementwise softmax (verified round 1, unchanged)
// ---------------------------------------------------------------------------
__global__ __launch_bounds__(256) void attn_scramble(
    const float* __restrict__ qkv, float* __restrict__ out)
{
    __shared__ float Ks[64][65];
    const int bid = blockIdx.x;
    const int hw6 = bid & 63;
    const int n   = (bid >> 6) & 7;
    const int b   = bid >> 9;
    const int kn  = (n + 7) & 7;
    const int t   = threadIdx.x;
    {
        const int hwlo = t & 63;
        const int d0   = t >> 6;
#pragma unroll
        for (int s = 0; s < 16; ++s) {
            const int dp = s * 4 + d0;
            Ks[dp][hwlo] =
                qkv[(size_t)(b * 4096 + dp * 64 + hw6) * 1536 + 512 + kn * 64 + hwlo];
        }
    }
    __syncthreads();
    const int row = t >> 2;
    const int tl  = t & 3;
    const size_t rbase = (size_t)(b * 4096 + hw6 * 64 + row) * 1536;
    float s[16];
    {
        const float* qp = qkv + rbase + n * 64 + tl * 16;
        float q[16];
#pragma unroll
        for (int u = 0; u < 4; ++u)
            *reinterpret_cast<float4*>(&q[u * 4]) =
                *reinterpret_cast<const float4*>(qp + u * 4);
        float m = -1e30f;
#pragma unroll
        for (int u = 0; u < 16; ++u) {
            s[u] = 0.125f * q[u] * Ks[tl * 16 + u][row];
            m = fmaxf(m, s[u]);
        }
        m = fmaxf(m, __shfl_xor(m, 1));
        m = fmaxf(m, __shfl_xor(m, 2));
        float sum = 0.f;
#pragma unroll
        for (int u = 0; u < 16; ++u) {
            s[u] = __expf(s[u] - m);
            sum += s[u];
        }
        sum += __shfl_xor(sum, 1);
        sum += __shfl_xor(sum, 2);
        const float inv = 1.0f / sum;
#pragma unroll
        for (int u = 0; u < 16; ++u) s[u] *= inv;
    }
    const float* vp = qkv + rbase + 1024 + kn * 64 + tl * 16;
    const int vb = b >> 3, fr = b & 7;
    float* op = out +
        ((size_t)(((vb * 8 + (hw6 >> 3)) * 64 + ((hw6 & 7) * 8 + (row >> 3))) * 64 +
                  ((row & 7) * 8 + n)) * 512) + fr * 64 + tl * 16;
#pragma unroll
    for (int u = 0; u < 4; ++u) {
        const float4 v = *reinterpret_cast<const float4*>(vp + u * 4);
        float4 o;
        o.x = s[u * 4 + 0] * v.x;
        o.y = s[u * 4 + 1] * v.y;
        o.z = s[u * 4 + 2] * v.z;
        o.w = s[u * 4 + 3] * v.w;
        *reinterpret_cast<float4*>(op + u * 4) = o;
    }
}

// ---------------------------------------------------------------------------
extern "C" void kernel_launch(void* const* d_in, const int* in_sizes, int n_in,
                              void* d_out, int out_size, void* d_ws, size_t ws_size,
                              hipStream_t stream) {
    const float* hs = (const float*)d_in[0];  // [65536,512]
    const float* w  = (const float*)d_in[1];  // [1536,512]
    const float* bq = (const float*)d_in[2];  // [1536]
    float* out = (float*)d_out;
    float* qkv = (float*)d_ws;                // 402,653,184 B (fits: r1/r3 ran)

    gemm_qkv_f16x2<<<6144, 256, 0, stream>>>(hs, w, bq, qkv);
    attn_scramble<<<8192, 256, 0, stream>>>(qkv, out);
}

// Round 8
// 420.312 us; speedup vs baseline: 1.4250x; 1.4250x over previous
//
#include <hip/hip_runtime.h>
#include <math.h>

// Geometry:
//   A = hidden_states [M=65536, K=512] fp32
//   W = w_qkv [N=1536, K=512] fp32, bias [1536]
//   qkv = A @ W^T + bias  -> [65536,1536] fp32 in d_ws
//   pass 2: scrambled elementwise softmax -> out [16,64,64,512] fp32
//
// GEMM: fp16 2-term split-MFMA (A = Ah + Al fp16; W -> fp16, RTZ).
// Round-4 depth-1 reg-stage structure (proven no-spill) + RAW BARRIERS:
// __syncthreads() forces vmcnt(0) drain (guide §5 barrier-drain stall);
// raw s_barrier + manual lgkmcnt(0) lets prefetch loads stay in flight
// across the barrier, covered by the whole MFMA phase (~500 cyc).

typedef _Float16 half8 __attribute__((ext_vector_type(8)));
typedef __fp16 fp16x2 __attribute__((ext_vector_type(2)));
typedef float f32x4 __attribute__((ext_vector_type(4)));

__device__ __forceinline__ half8 pk8(const float4 x, const float4 y) {
    fp16x2 a = __builtin_amdgcn_cvt_pkrtz(x.x, x.y);
    fp16x2 b = __builtin_amdgcn_cvt_pkrtz(x.z, x.w);
    fp16x2 c = __builtin_amdgcn_cvt_pkrtz(y.x, y.y);
    fp16x2 d = __builtin_amdgcn_cvt_pkrtz(y.z, y.w);
    half8 r;
    r[0] = (_Float16)a[0]; r[1] = (_Float16)a[1];
    r[2] = (_Float16)b[0]; r[3] = (_Float16)b[1];
    r[4] = (_Float16)c[0]; r[5] = (_Float16)c[1];
    r[6] = (_Float16)d[0]; r[7] = (_Float16)d[1];
    return r;
}
__device__ __forceinline__ void pk8_hilo(const float4 x, const float4 y,
                                         half8& h, half8& l) {
    h = pk8(x, y);
    float4 rx, ry;
    rx.x = x.x - (float)h[0]; rx.y = x.y - (float)h[1];
    rx.z = x.z - (float)h[2]; rx.w = x.w - (float)h[3];
    ry.x = y.x - (float)h[4]; ry.y = y.y - (float)h[5];
    ry.z = y.z - (float)h[6]; ry.w = y.w - (float)h[7];
    l = pk8(rx, ry);
}

// ---------------------------------------------------------------------------
// Kernel 1: C[65536,1536] = A @ W^T + bias.
// BM=BN=128, BK=32, 256 threads (2x2 waves, 64x64/wave), LDS double-buffered.
// Per buffer (halfword offsets): Ah [0,4096), Al [4096,8192), Wh [8192,12288).
// Chunk swizzle (2-bit): 16B chunk c of row r stored at phys c ^ ((r>>1)&3).
// ---------------------------------------------------------------------------
__global__ __launch_bounds__(256, 3) void gemm_qkv_f16x2(
    const float* __restrict__ A,
    const float* __restrict__ W,
    const float* __restrict__ bias,
    float* __restrict__ C)
{
    __shared__ __align__(16) _Float16 lds[24576];   // 48 KB (2 x 24 KB)

    // XCD swizzle: 6144 blocks (%8==0), n-fastest within an XCD for A reuse
    const int lin = blockIdx.x;
    const int swz = (lin & 7) * 768 + (lin >> 3);
    const int nt = swz % 12, mt = swz / 12;
    const int row0 = mt * 128, col0 = nt * 128;

    const int tid  = threadIdx.x;
    const int wid  = tid >> 6;
    const int lane = tid & 63;
    const int wm   = wid >> 1;    // 0..1
    const int wn   = wid & 1;     // 0..1
    const int l15  = lane & 15;
    const int kq   = lane >> 4;   // 0..3

    // staging: thread t covers row ra = t>>1 (A and W rows), k = kh..kh+15
    const int ra = tid >> 1;
    const int kh = (tid & 1) * 16;
    const float* Ag = A + (size_t)(row0 + ra) * 512 + kh;
    const float* Wg = W + (size_t)(col0 + ra) * 512 + kh;
    const int rs  = (ra >> 1) & 3;             // 2-bit row swizzle
    const int wc0 = (((kh >> 3) + 0) ^ rs) * 8;
    const int wc1 = (((kh >> 3) + 1) ^ rs) * 8;

    f32x4 acc[4][4];
#pragma unroll
    for (int i = 0; i < 4; ++i)
#pragma unroll
        for (int j = 0; j < 4; ++j) acc[i][j] = (f32x4)0.f;

    // depth-1 prefetch registers (statically indexed, proven no-spill in r4)
    float4 ar[4], wr[4];
#pragma unroll
    for (int u = 0; u < 4; ++u) {
        ar[u] = *reinterpret_cast<const float4*>(Ag + u * 4);
        wr[u] = *reinterpret_cast<const float4*>(Wg + u * 4);
    }

    for (int it = 0; it < 16; ++it) {
        _Float16* bp = lds + (it & 1) * 12288;

        // convert once (compiler inserts counted vmcnt before first use)
        half8 h0, l0, h1, l1;
        pk8_hilo(ar[0], ar[1], h0, l0);
        pk8_hilo(ar[2], ar[3], h1, l1);
        const half8 wv0 = pk8(wr[0], wr[1]);
        const half8 wv1 = pk8(wr[2], wr[3]);
        *reinterpret_cast<half8*>(bp + ra * 32 + wc0)        = h0;
        *reinterpret_cast<half8*>(bp + ra * 32 + wc1)        = h1;
        *reinterpret_cast<half8*>(bp + 4096 + ra * 32 + wc0) = l0;
        *reinterpret_cast<half8*>(bp + 4096 + ra * 32 + wc1) = l1;
        *reinterpret_cast<half8*>(bp + 8192 + ra * 32 + wc0) = wv0;
        *reinterpret_cast<half8*>(bp + 8192 + ra * 32 + wc1) = wv1;

        // prefetch next K-tile into regs (stays in flight across raw barrier)
        if (it < 15) {
            const int kb = (it + 1) * 32;
#pragma unroll
            for (int u = 0; u < 4; ++u) {
                ar[u] = *reinterpret_cast<const float4*>(Ag + kb + u * 4);
                wr[u] = *reinterpret_cast<const float4*>(Wg + kb + u * 4);
            }
        }

        // raw barrier: drain LDS writes only; global loads NOT drained
        asm volatile("s_waitcnt lgkmcnt(0)" ::: "memory");
        __builtin_amdgcn_s_barrier();
        asm volatile("" ::: "memory");

        // compute from buf[it&1]
        const _Float16* cp = lds + (it & 1) * 12288;
        half8 ah[4], al[4];
#pragma unroll
        for (int mf = 0; mf < 4; ++mf) {
            const int r  = wm * 64 + mf * 16 + l15;
            const int ph = (kq ^ ((r >> 1) & 3)) * 8;
            ah[mf] = *reinterpret_cast<const half8*>(cp + r * 32 + ph);
            al[mf] = *reinterpret_cast<const half8*>(cp + 4096 + r * 32 + ph);
        }
#pragma unroll
        for (int nf = 0; nf < 4; ++nf) {
            const int rb = wn * 64 + nf * 16 + l15;
            const int ph = (kq ^ ((rb >> 1) & 3)) * 8;
            const half8 wv = *reinterpret_cast<const half8*>(cp + 8192 + rb * 32 + ph);
#pragma unroll
            for (int mf = 0; mf < 4; ++mf) {
                acc[mf][nf] = __builtin_amdgcn_mfma_f32_16x16x32_f16(
                    ah[mf], wv, acc[mf][nf], 0, 0, 0);
                acc[mf][nf] = __builtin_amdgcn_mfma_f32_16x16x32_f16(
                    al[mf], wv, acc[mf][nf], 0, 0, 0);
            }
        }
    }

    // epilogue: C/D layout col = lane&15, row = (lane>>4)*4 + j
    float bv[4];
#pragma unroll
    for (int nf = 0; nf < 4; ++nf)
        bv[nf] = bias[col0 + wn * 64 + nf * 16 + l15];

#pragma unroll
    for (int mf = 0; mf < 4; ++mf)
#pragma unroll
        for (int nf = 0; nf < 4; ++nf) {
            const int c = col0 + wn * 64 + nf * 16 + l15;
#pragma unroll
            for (int j = 0; j < 4; ++j) {
                const int r = row0 + wm * 64 + mf * 16 + kq * 4 + j;
                C[(size_t)r * 1536 + c] = acc[mf][nf][j] + bv[nf];
            }
        }
}

// ---------------------------------------------------------------------------
// Kernel 2: scrambled elementwise softmax (verified round 1, unchanged)
// ---------------------------------------------------------------------------
__global__ __launch_bounds__(256) void attn_scramble(
    const float* __restrict__ qkv, float* __restrict__ out)
{
    __shared__ float Ks[64][65];
    const int bid = blockIdx.x;
    const int hw6 = bid & 63;
    const int n   = (bid >> 6) & 7;
    const int b   = bid >> 9;
    const int kn  = (n + 7) & 7;
    const int t   = threadIdx.x;
    {
        const int hwlo = t & 63;
        const int d0   = t >> 6;
#pragma unroll
        for (int s = 0; s < 16; ++s) {
            const int dp = s * 4 + d0;
            Ks[dp][hwlo] =
                qkv[(size_t)(b * 4096 + dp * 64 + hw6) * 1536 + 512 + kn * 64 + hwlo];
        }
    }
    __syncthreads();
    const int row = t >> 2;
    const int tl  = t & 3;
    const size_t rbase = (size_t)(b * 4096 + hw6 * 64 + row) * 1536;
    float s[16];
    {
        const float* qp = qkv + rbase + n * 64 + tl * 16;
        float q[16];
#pragma unroll
        for (int u = 0; u < 4; ++u)
            *reinterpret_cast<float4*>(&q[u * 4]) =
                *reinterpret_cast<const float4*>(qp + u * 4);
        float m = -1e30f;
#pragma unroll
        for (int u = 0; u < 16; ++u) {
            s[u] = 0.125f * q[u] * Ks[tl * 16 + u][row];
            m = fmaxf(m, s[u]);
        }
        m = fmaxf(m, __shfl_xor(m, 1));
        m = fmaxf(m, __shfl_xor(m, 2));
        float sum = 0.f;
#pragma unroll
        for (int u = 0; u < 16; ++u) {
            s[u] = __expf(s[u] - m);
            sum += s[u];
        }
        sum += __shfl_xor(sum, 1);
        sum += __shfl_xor(sum, 2);
        const float inv = 1.0f / sum;
#pragma unroll
        for (int u = 0; u < 16; ++u) s[u] *= inv;
    }
    const float* vp = qkv + rbase + 1024 + kn * 64 + tl * 16;
    const int vb = b >> 3, fr = b & 7;
    float* op = out +
        ((size_t)(((vb * 8 + (hw6 >> 3)) * 64 + ((hw6 & 7) * 8 + (row >> 3))) * 64 +
                  ((row & 7) * 8 + n)) * 512) + fr * 64 + tl * 16;
#pragma unroll
    for (int u = 0; u < 4; ++u) {
        const float4 v = *reinterpret_cast<const float4*>(vp + u * 4);
        float4 o;
        o.x = s[u * 4 + 0] * v.x;
        o.y = s[u * 4 + 1] * v.y;
        o.z = s[u * 4 + 2] * v.z;
        o.w = s[u * 4 + 3] * v.w;
        *reinterpret_cast<float4*>(op + u * 4) = o;
    }
}

// ---------------------------------------------------------------------------
extern "C" void kernel_launch(void* const* d_in, const int* in_sizes, int n_in,
                              void* d_out, int out_size, void* d_ws, size_t ws_size,
                              hipStream_t stream) {
    const float* hs = (const float*)d_in[0];  // [65536,512]
    const float* w  = (const float*)d_in[1];  // [1536,512]
    const float* bq = (const float*)d_in[2];  // [1536]
    float* out = (float*)d_out;
    float* qkv = (float*)d_ws;                // 402,653,184 B (fits: r1/r3 ran)

    gemm_qkv_f16x2<<<6144, 256, 0, stream>>>(hs, w, bq, qkv);
    attn_scramble<<<8192, 256, 0, stream>>>(qkv, out);
}